// Round 18
// baseline (192.214 us; speedup 1.0000x reference)
//
#include <hip/hip_runtime.h>
#include <hip/hip_fp16.h>

#define N_NODES 50000
#define N_EDGES 800000
#define D 64
#define DHID 100
#define NTILES (N_NODES / 16)                   // 3125
#define NCT 7                                   // head col-tiles (112 cols padded)
#define CAP 64                                  // fixed slots per node
#define NGROUPS 4                               // dst-range groups (2 XCDs per group)
#define NSLICES 780                             // fill blocks per group
#define FILL_BLOCKS (NGROUPS * NSLICES)         // 3120
#define MM_BLOCKS ((NTILES + 3) / 4)            // 782
#define DST_PER_GROUP (N_NODES / NGROUPS)       // 12500

typedef unsigned short ushort;
typedef unsigned int uint;
typedef __attribute__((ext_vector_type(8))) short s16x8;
typedef __attribute__((ext_vector_type(4))) float f32x4;

#define MFMA16(A, B, C) __builtin_amdgcn_mfma_f32_16x16x32_bf16((A), (B), (C), 0, 0, 0)

__device__ __forceinline__ float swishf(float x) { return x / (1.0f + __expf(-x)); }

__device__ __forceinline__ ushort f2bf(float f) {   // RTNE fp32 -> bf16
    uint u = __float_as_uint(f);
    uint r = (u + 0x7fffu + ((u >> 16) & 1u)) >> 16;
    return (ushort)r;
}
__device__ __forceinline__ float bf2f(ushort h) { return __uint_as_float((uint)h << 16); }
__device__ __forceinline__ float bf_lo(uint d) { return __uint_as_float(d << 16); }
__device__ __forceinline__ float bf_hi(uint d) { return __uint_as_float(d & 0xffff0000u); }

__device__ __forceinline__ float hwf(uint e) {
    return __half2float(__ushort_as_half((ushort)(e >> 16)));
}

__device__ __forceinline__ void accum8(float* acc, uint4 v, float w) {
    acc[0] = fmaf(w, bf_lo(v.x), acc[0]);
    acc[1] = fmaf(w, bf_hi(v.x), acc[1]);
    acc[2] = fmaf(w, bf_lo(v.y), acc[2]);
    acc[3] = fmaf(w, bf_hi(v.y), acc[3]);
    acc[4] = fmaf(w, bf_lo(v.z), acc[4]);
    acc[5] = fmaf(w, bf_hi(v.z), acc[5]);
    acc[6] = fmaf(w, bf_lo(v.w), acc[6]);
    acc[7] = fmaf(w, bf_hi(v.w), acc[7]);
}

// two-node interleaved wave gather: 2 independent csr->H chains in flight
// (2 csr uint4 + 8 H uint4 loads per iter). Results on j==0 lanes.
__device__ __forceinline__ void gather2(const ushort* __restrict__ H,
                                        const uint* __restrict__ bA,
                                        const uint* __restrict__ bB,
                                        int dA, int dB, int j, int fg,
                                        float* accA, float* accB) {
#pragma unroll
    for (int t = 0; t < 8; ++t) { accA[t] = 0.f; accB[t] = 0.f; }
    int mx = max(dA, dB);
    for (int base = 0; base < mx; base += 32) {
        int s0 = base + j * 4;
        uint4 eA = *((const uint4*)(bA + s0));
        uint4 eB = *((const uint4*)(bB + s0));
        float wA0 = (s0 + 0 < dA) ? hwf(eA.x) : 0.f;
        float wA1 = (s0 + 1 < dA) ? hwf(eA.y) : 0.f;
        float wA2 = (s0 + 2 < dA) ? hwf(eA.z) : 0.f;
        float wA3 = (s0 + 3 < dA) ? hwf(eA.w) : 0.f;
        float wB0 = (s0 + 0 < dB) ? hwf(eB.x) : 0.f;
        float wB1 = (s0 + 1 < dB) ? hwf(eB.y) : 0.f;
        float wB2 = (s0 + 2 < dB) ? hwf(eB.z) : 0.f;
        float wB3 = (s0 + 3 < dB) ? hwf(eB.w) : 0.f;
        uint a0 = min(eA.x & 0xffffu, (uint)(N_NODES - 1));
        uint a1 = min(eA.y & 0xffffu, (uint)(N_NODES - 1));
        uint a2 = min(eA.z & 0xffffu, (uint)(N_NODES - 1));
        uint a3 = min(eA.w & 0xffffu, (uint)(N_NODES - 1));
        uint b0 = min(eB.x & 0xffffu, (uint)(N_NODES - 1));
        uint b1 = min(eB.y & 0xffffu, (uint)(N_NODES - 1));
        uint b2 = min(eB.z & 0xffffu, (uint)(N_NODES - 1));
        uint b3 = min(eB.w & 0xffffu, (uint)(N_NODES - 1));
        uint4 vA0 = *((const uint4*)(H + ((size_t)a0 << 6) + (fg << 3)));
        uint4 vA1 = *((const uint4*)(H + ((size_t)a1 << 6) + (fg << 3)));
        uint4 vA2 = *((const uint4*)(H + ((size_t)a2 << 6) + (fg << 3)));
        uint4 vA3 = *((const uint4*)(H + ((size_t)a3 << 6) + (fg << 3)));
        uint4 vB0 = *((const uint4*)(H + ((size_t)b0 << 6) + (fg << 3)));
        uint4 vB1 = *((const uint4*)(H + ((size_t)b1 << 6) + (fg << 3)));
        uint4 vB2 = *((const uint4*)(H + ((size_t)b2 << 6) + (fg << 3)));
        uint4 vB3 = *((const uint4*)(H + ((size_t)b3 << 6) + (fg << 3)));
        accum8(accA, vA0, wA0);
        accum8(accB, vB0, wB0);
        accum8(accA, vA1, wA1);
        accum8(accB, vB1, wB1);
        accum8(accA, vA2, wA2);
        accum8(accB, vB2, wB2);
        accum8(accA, vA3, wA3);
        accum8(accB, vB3, wB3);
    }
#pragma unroll
    for (int t = 0; t < 8; ++t) {
        accA[t] += __shfl_xor(accA[t], 8, 64);
        accA[t] += __shfl_xor(accA[t], 16, 64);
        accA[t] += __shfl_xor(accA[t], 32, 64);
        accB[t] += __shfl_xor(accB[t], 8, 64);
        accB[t] += __shfl_xor(accB[t], 16, 64);
        accB[t] += __shfl_xor(accB[t], 32, 64);
    }
}

// ---- fused: XCD-partitioned fill + H1 = X@W1 + weight-split prep (2 blocks) ----
__global__ __launch_bounds__(256) void fill_and_l1(const int* __restrict__ src,
                                                   const int* __restrict__ dst,
                                                   const float* __restrict__ w,
                                                   int* __restrict__ deg,
                                                   uint* __restrict__ csr,
                                                   const float* __restrict__ X,
                                                   const float* __restrict__ W,
                                                   const float* __restrict__ W2,
                                                   const float* __restrict__ Wd,
                                                   short* __restrict__ W2T2,
                                                   short* __restrict__ WdT2,
                                                   ushort* __restrict__ H) {
    __shared__ __align__(16) short sBT[2][D][72];    // 18.4 KB (aliased as rep later)
    int tid = threadIdx.x;

    if (blockIdx.x < FILL_BLOCKS) {
        const int g = blockIdx.x & (NGROUPS - 1);
        const int s = blockIdx.x >> 2;               // slice 0..NSLICES-1
        const int lo = g * DST_PER_GROUP;
        const int hi = lo + DST_PER_GROUP;
        for (int e = s * 256 + tid; e < N_EDGES; e += NSLICES * 256) {
            int d = dst[e];                          // L3 absorbs the 4x re-scan
            if (d >= lo && d < hi) {
                uint hw = (uint)__half_as_ushort(__float2half_rn(w[e]));
                uint payload = (uint)src[e] | (hw << 16);
                int r = atomicAdd(&deg[d], 1);
                r = min(r, CAP - 1);   // safety clamp
                csr[(d << 6) + r] = payload;
            }
        }
        return;
    }

    if (blockIdx.x >= FILL_BLOCKS + MM_BLOCKS) {
        // ---------- weight-split prep ----------
        if (blockIdx.x == FILL_BLOCKS + MM_BLOCKS) {
            for (int idx = tid; idx < D * D; idx += 256) {
                int k = idx >> 6, c = idx & 63;
                float wv = W2[idx];
                ushort hi = f2bf(wv);
                W2T2[(size_t)c * D + k] = (short)hi;
                W2T2[(size_t)(D + c) * D + k] = (short)f2bf(wv - bf2f(hi));
            }
        } else {
            for (int idx = tid; idx < NCT * 16 * D; idx += 256) {
                int jj = idx >> 6, k = idx & 63;
                float wv = (jj < DHID) ? Wd[k * DHID + jj] : 0.f;
                ushort hi = f2bf(wv);
                WdT2[(size_t)jj * D + k] = (short)hi;
                WdT2[(size_t)(NCT * 16 + jj) * D + k] = (short)f2bf(wv - bf2f(hi));
            }
        }
        return;
    }

    // ---------- mfma_l1 path ----------
    for (int idx = tid; idx < D * D; idx += 256) {
        int k = idx >> 6, c = idx & 63;
        float wv = W[idx];
        ushort hi = f2bf(wv);
        sBT[0][c][k] = (short)hi;
        sBT[1][c][k] = (short)f2bf(wv - bf2f(hi));
    }
    __syncthreads();
    int wv_ = tid >> 6, lane = tid & 63, quad = lane >> 4, m = lane & 15;
    int tile = min((blockIdx.x - FILL_BLOCKS) * 4 + wv_, NTILES - 1);  // clamp (dup stores ok)
    int node0 = tile * 16;

    f32x4 acc[4] = {{0,0,0,0},{0,0,0,0},{0,0,0,0},{0,0,0,0}};
#pragma unroll
    for (int kt = 0; kt < 2; ++kt) {
        int k0 = kt * 32 + quad * 8;
        const float* xp = X + ((size_t)(node0 + m) << 6) + k0;
        float4 xa = *((const float4*)xp);
        float4 xb = *((const float4*)(xp + 4));
        float xv[8] = {xa.x, xa.y, xa.z, xa.w, xb.x, xb.y, xb.z, xb.w};
        s16x8 ahi, alo;
#pragma unroll
        for (int jj = 0; jj < 8; ++jj) {
            ushort hi = f2bf(xv[jj]);
            ahi[jj] = (short)hi;
            alo[jj] = (short)f2bf(xv[jj] - bf2f(hi));
        }
#pragma unroll
        for (int ct = 0; ct < 4; ++ct) {
            int n = ct * 16 + m;
            s16x8 bhi = *((const s16x8*)&sBT[0][n][k0]);
            s16x8 blo = *((const s16x8*)&sBT[1][n][k0]);
            acc[ct] = MFMA16(ahi, bhi, acc[ct]);
            acc[ct] = MFMA16(ahi, blo, acc[ct]);
            acc[ct] = MFMA16(alo, bhi, acc[ct]);
        }
    }
    __syncthreads();   // safe to alias rep over sBT
    short (*rep)[16][72] = (short(*)[16][72])&sBT[0][0][0];
#pragma unroll
    for (int ct = 0; ct < 4; ++ct)
#pragma unroll
        for (int r = 0; r < 4; ++r)
            rep[wv_][quad * 4 + r][ct * 16 + m] = (short)f2bf(acc[ct][r]);
#pragma unroll
    for (int half = 0; half < 2; ++half) {
        int r = (lane >> 3) + half * 8;
        int c0 = (lane & 7) * 8;
        s16x8 v = *((const s16x8*)&rep[wv_][r][c0]);
        *((s16x8*)(H + ((size_t)(node0 + r) << 6) + c0)) = v;
    }
}

// ---------------- gather + bias + swish -> bf16 activation (layer 1) ----------------
// 2 nodes per wave, interleaved chains
__global__ __launch_bounds__(256) void gather_act(const ushort* __restrict__ H,
                                                  const int* __restrict__ deg,
                                                  const uint* __restrict__ csr,
                                                  const float* __restrict__ bias,
                                                  ushort* __restrict__ actOut) {
    int tid = threadIdx.x;
    int wave = tid >> 6, lane = tid & 63;
    int j = lane >> 3, fg = lane & 7;
    int nodeA = blockIdx.x * 8 + wave * 2;
    int nodeB = nodeA + 1;
    int dA = min(deg[nodeA], CAP);
    int dB = min(deg[nodeB], CAP);
    const uint* bA = csr + ((size_t)nodeA << 6);
    const uint* bB = csr + ((size_t)nodeB << 6);

    float accA[8], accB[8];
    gather2(H, bA, bB, dA, dB, j, fg, accA, accB);
    if (j == 0) {
        float4 ba = ((const float4*)bias)[fg * 2];
        float4 bb = ((const float4*)bias)[fg * 2 + 1];
        uint4 u;
        u.x = (uint)f2bf(swishf(accA[0] + ba.x)) | ((uint)f2bf(swishf(accA[1] + ba.y)) << 16);
        u.y = (uint)f2bf(swishf(accA[2] + ba.z)) | ((uint)f2bf(swishf(accA[3] + ba.w)) << 16);
        u.z = (uint)f2bf(swishf(accA[4] + bb.x)) | ((uint)f2bf(swishf(accA[5] + bb.y)) << 16);
        u.w = (uint)f2bf(swishf(accA[6] + bb.z)) | ((uint)f2bf(swishf(accA[7] + bb.w)) << 16);
        *((uint4*)(actOut + ((size_t)nodeA << 6) + (fg << 3))) = u;
        uint4 v;
        v.x = (uint)f2bf(swishf(accB[0] + ba.x)) | ((uint)f2bf(swishf(accB[1] + ba.y)) << 16);
        v.y = (uint)f2bf(swishf(accB[2] + ba.z)) | ((uint)f2bf(swishf(accB[3] + ba.w)) << 16);
        v.z = (uint)f2bf(swishf(accB[4] + bb.x)) | ((uint)f2bf(swishf(accB[5] + bb.y)) << 16);
        v.w = (uint)f2bf(swishf(accB[6] + bb.z)) | ((uint)f2bf(swishf(accB[7] + bb.w)) << 16);
        *((uint4*)(actOut + ((size_t)nodeB << 6) + (fg << 3))) = v;
    }
}

// ---- fused: layer-2 gather + W2 matmul + bias + swish + MLP head, one 16-node tile/block ----
__global__ __launch_bounds__(256) void gather_tail(const ushort* __restrict__ act1,
                                                   const int* __restrict__ deg,
                                                   const uint* __restrict__ csr,
                                                   const short* __restrict__ W2T2,
                                                   const float* __restrict__ b2,
                                                   const short* __restrict__ WdT2,
                                                   const float* __restrict__ bd,
                                                   const float* __restrict__ Wo,
                                                   const float* __restrict__ bo,
                                                   float* __restrict__ out) {
    __shared__ __align__(16) float sAgg[16][72];    // 4.6 KB fp32 aggregates
    __shared__ __align__(16) short sAct2[16][72];   // 2.3 KB bf16 act2 tile
    __shared__ float sPart[4][16];                  // per-wave head partials
    int tid = threadIdx.x;
    int wv = tid >> 6, lane = tid & 63;
    int j = lane >> 3, fg = lane & 7;
    int quad = lane >> 4, m = lane & 15;
    int node0 = blockIdx.x * 16;

    // ---- phase 0: 4 nodes per wave, as 2 interleaved pairs ----
#pragma unroll
    for (int p = 0; p < 2; ++p) {
        int nl = wv * 4 + p * 2;
        int nodeA = node0 + nl, nodeB = nodeA + 1;
        int dA = min(deg[nodeA], CAP);
        int dB = min(deg[nodeB], CAP);
        const uint* bA = csr + ((size_t)nodeA << 6);
        const uint* bB = csr + ((size_t)nodeB << 6);
        float accA[8], accB[8];
        gather2(act1, bA, bB, dA, dB, j, fg, accA, accB);
        if (j == 0) {
            float4 uA0 = {accA[0], accA[1], accA[2], accA[3]};
            float4 uA1 = {accA[4], accA[5], accA[6], accA[7]};
            *((float4*)&sAgg[nl][fg * 8]) = uA0;
            *((float4*)&sAgg[nl][fg * 8 + 4]) = uA1;
            float4 uB0 = {accB[0], accB[1], accB[2], accB[3]};
            float4 uB1 = {accB[4], accB[5], accB[6], accB[7]};
            *((float4*)&sAgg[nl + 1][fg * 8]) = uB0;
            *((float4*)&sAgg[nl + 1][fg * 8 + 4]) = uB1;
        }
    }
    __syncthreads();

    // ---- phase A: act2 = swish(agg @ W2 + b2), wave wv -> col-tile wv ----
    {
        f32x4 acc = {0, 0, 0, 0};
        int n = wv * 16 + m;
#pragma unroll
        for (int kt = 0; kt < 2; ++kt) {
            int k0 = kt * 32 + quad * 8;
            float4 xa = *((const float4*)&sAgg[m][k0]);
            float4 xb = *((const float4*)&sAgg[m][k0 + 4]);
            float xv[8] = {xa.x, xa.y, xa.z, xa.w, xb.x, xb.y, xb.z, xb.w};
            s16x8 ahi, alo;
#pragma unroll
            for (int jj = 0; jj < 8; ++jj) {
                ushort hi = f2bf(xv[jj]);
                ahi[jj] = (short)hi;
                alo[jj] = (short)f2bf(xv[jj] - bf2f(hi));
            }
            s16x8 bhi = *((const s16x8*)(W2T2 + (size_t)n * D + k0));
            s16x8 blo = *((const s16x8*)(W2T2 + (size_t)(D + n) * D + k0));
            acc = MFMA16(ahi, bhi, acc);
            acc = MFMA16(ahi, blo, acc);
            acc = MFMA16(alo, bhi, acc);
        }
        float bv = b2[n];
#pragma unroll
        for (int r = 0; r < 4; ++r)
            sAct2[quad * 4 + r][n] = (short)f2bf(swishf(acc[r] + bv));
    }
    __syncthreads();

    // ---- phase B: head over col-tiles {wv, wv+4} ----
    float part[4] = {0, 0, 0, 0};
#pragma unroll
    for (int cc = 0; cc < 2; ++cc) {
        int ct = wv + cc * 4;
        if (ct < NCT) {
            f32x4 acc = {0, 0, 0, 0};
            int n = ct * 16 + m;
#pragma unroll
            for (int kt = 0; kt < 2; ++kt) {
                int k0 = kt * 32 + quad * 8;
                s16x8 a = *((const s16x8*)&sAct2[m][k0]);
                s16x8 bhi = *((const s16x8*)(WdT2 + (size_t)n * D + k0));
                s16x8 blo = *((const s16x8*)(WdT2 + (size_t)(NCT * 16 + n) * D + k0));
                acc = MFMA16(a, bhi, acc);
                acc = MFMA16(a, blo, acc);
            }
            float bdv = (n < DHID) ? bd[n] : 0.f;
            float wov = (n < DHID) ? Wo[n] : 0.f;
#pragma unroll
            for (int r = 0; r < 4; ++r)
                part[r] = fmaf(swishf(acc[r] + bdv), wov, part[r]);
        }
    }
#pragma unroll
    for (int r = 0; r < 4; ++r) {
        part[r] += __shfl_xor(part[r], 1, 64);
        part[r] += __shfl_xor(part[r], 2, 64);
        part[r] += __shfl_xor(part[r], 4, 64);
        part[r] += __shfl_xor(part[r], 8, 64);
    }
    if (m == 0) {
#pragma unroll
        for (int r = 0; r < 4; ++r)
            sPart[wv][quad * 4 + r] = part[r];
    }
    __syncthreads();
    if (tid < 16) {
        float z = sPart[0][tid] + sPart[1][tid] + sPart[2][tid] + sPart[3][tid] + bo[0];
        out[node0 + tid] = 1.f / (1.f + __expf(-z));
    }
}

extern "C" void kernel_launch(void* const* d_in, const int* in_sizes, int n_in,
                              void* d_out, int out_size, void* d_ws, size_t ws_size,
                              hipStream_t stream) {
    const float* x   = (const float*)d_in[0];
    const int* esrc  = (const int*)d_in[1];
    const int* edst  = (const int*)d_in[2];
    const float* ew  = (const float*)d_in[3];
    const float* W1  = (const float*)d_in[4];
    const float* b1  = (const float*)d_in[5];
    const float* W2  = (const float*)d_in[6];
    const float* b2  = (const float*)d_in[7];
    const float* Wd  = (const float*)d_in[8];
    const float* bd  = (const float*)d_in[9];
    const float* Wo  = (const float*)d_in[10];
    const float* bo  = (const float*)d_in[11];
    float* out = (float*)d_out;

    char* ws = (char*)d_ws;
    ushort* H1   = (ushort*)ws;  ws += (size_t)N_NODES * D * sizeof(ushort);   // 6.4 MB
    ushort* act1 = (ushort*)ws;  ws += (size_t)N_NODES * D * sizeof(ushort);   // 6.4 MB
    uint* csr    = (uint*)ws;    ws += (size_t)N_NODES * CAP * sizeof(uint);   // 12.8 MB (not zeroed)
    int* deg     = (int*)ws;     ws += (size_t)N_NODES * sizeof(int);          // 200 KB
    short* W2T2  = (short*)ws;   ws += (size_t)2 * D * D * sizeof(short);      // 16 KB
    short* WdT2  = (short*)ws;   ws += (size_t)2 * NCT * 16 * D * sizeof(short); // 28.7 KB

    // ---- only deg needs zeroing (200 KB) ----
    hipMemsetAsync(deg, 0, (size_t)N_NODES * sizeof(int), stream);

    // ---- fused: XCD-partitioned fill + layer-1 matmul + weight prep ----
    fill_and_l1<<<FILL_BLOCKS + MM_BLOCKS + 2, 256, 0, stream>>>(
        esrc, edst, ew, deg, csr, x, W1, W2, Wd, W2T2, WdT2, H1);

    // ---- layer 1 gather (+bias+swish), 2 nodes/wave ----
    gather_act<<<N_NODES / 8, 256, 0, stream>>>(H1, deg, csr, b1, act1);

    // ---- fused: layer-2 gather + W2 matmul + swish + MLP head ----
    gather_tail<<<NTILES, 256, 0, stream>>>(act1, deg, csr, W2T2, b2, WdT2, bd, Wo, bo, out);
}

// Round 19
// 188.944 us; speedup vs baseline: 1.0173x; 1.0173x over previous
//
#include <hip/hip_runtime.h>
#include <hip/hip_fp16.h>

#define N_NODES 50000
#define N_EDGES 800000
#define D 64
#define DHID 100
#define NTILES (N_NODES / 16)                   // 3125
#define NCT 7                                   // head col-tiles (112 cols padded)
#define CAP 64                                  // fixed slots per node
#define NGROUPS 4                               // dst-range groups (2 XCDs per group)
#define NSLICES 780                             // fill blocks per group
#define FILL_BLOCKS (NGROUPS * NSLICES)         // 3120
#define MM_BLOCKS ((NTILES + 3) / 4)            // 782
#define DST_PER_GROUP (N_NODES / NGROUPS)       // 12500

typedef unsigned short ushort;
typedef unsigned int uint;
typedef __attribute__((ext_vector_type(8))) short s16x8;
typedef __attribute__((ext_vector_type(4))) float f32x4;

#define MFMA16(A, B, C) __builtin_amdgcn_mfma_f32_16x16x32_bf16((A), (B), (C), 0, 0, 0)

__device__ __forceinline__ float swishf(float x) { return x / (1.0f + __expf(-x)); }

__device__ __forceinline__ ushort f2bf(float f) {   // RTNE fp32 -> bf16
    uint u = __float_as_uint(f);
    uint r = (u + 0x7fffu + ((u >> 16) & 1u)) >> 16;
    return (ushort)r;
}
__device__ __forceinline__ float bf2f(ushort h) { return __uint_as_float((uint)h << 16); }
__device__ __forceinline__ float bf_lo(uint d) { return __uint_as_float(d << 16); }
__device__ __forceinline__ float bf_hi(uint d) { return __uint_as_float(d & 0xffff0000u); }

__device__ __forceinline__ float hwf(uint e) {
    return __half2float(__ushort_as_half((ushort)(e >> 16)));
}

__device__ __forceinline__ void accum8(float* acc, uint4 v, float w) {
    acc[0] = fmaf(w, bf_lo(v.x), acc[0]);
    acc[1] = fmaf(w, bf_hi(v.x), acc[1]);
    acc[2] = fmaf(w, bf_lo(v.y), acc[2]);
    acc[3] = fmaf(w, bf_hi(v.y), acc[3]);
    acc[4] = fmaf(w, bf_lo(v.z), acc[4]);
    acc[5] = fmaf(w, bf_hi(v.z), acc[5]);
    acc[6] = fmaf(w, bf_lo(v.w), acc[6]);
    acc[7] = fmaf(w, bf_hi(v.w), acc[7]);
}

// per-node wave gather: lane = slot-quad j (lane>>3) x feature-group fg (lane&7).
// One uint4 bucket load covers 4 edge slots (csr pad slots hold garbage: weight
// predicated to 0, src clamped to a valid node). Result in acc[8] on j==0 lanes.
__device__ __forceinline__ void gather_node(const ushort* __restrict__ H,
                                            const uint* __restrict__ bucket,
                                            int degv, int j, int fg, float* acc) {
#pragma unroll
    for (int t = 0; t < 8; ++t) acc[t] = 0.f;
    for (int base = 0; base < degv; base += 32) {
        int s0 = base + j * 4;                     // this lane's 4 slots
        uint4 e = *((const uint4*)(bucket + s0));
        float w0 = (s0 + 0 < degv) ? hwf(e.x) : 0.f;
        float w1 = (s0 + 1 < degv) ? hwf(e.y) : 0.f;
        float w2 = (s0 + 2 < degv) ? hwf(e.z) : 0.f;
        float w3 = (s0 + 3 < degv) ? hwf(e.w) : 0.f;
        uint s0i = min(e.x & 0xffffu, (uint)(N_NODES - 1));
        uint s1i = min(e.y & 0xffffu, (uint)(N_NODES - 1));
        uint s2i = min(e.z & 0xffffu, (uint)(N_NODES - 1));
        uint s3i = min(e.w & 0xffffu, (uint)(N_NODES - 1));
        uint4 v0 = *((const uint4*)(H + ((size_t)s0i << 6) + (fg << 3)));
        uint4 v1 = *((const uint4*)(H + ((size_t)s1i << 6) + (fg << 3)));
        uint4 v2 = *((const uint4*)(H + ((size_t)s2i << 6) + (fg << 3)));
        uint4 v3 = *((const uint4*)(H + ((size_t)s3i << 6) + (fg << 3)));
        accum8(acc, v0, w0);
        accum8(acc, v1, w1);
        accum8(acc, v2, w2);
        accum8(acc, v3, w3);
    }
#pragma unroll
    for (int t = 0; t < 8; ++t) {
        acc[t] += __shfl_xor(acc[t], 8, 64);
        acc[t] += __shfl_xor(acc[t], 16, 64);
        acc[t] += __shfl_xor(acc[t], 32, 64);
    }
}

// ---- fused: XCD-partitioned fill + H1 = X@W1 + weight-split prep (2 blocks) ----
__global__ __launch_bounds__(256) void fill_and_l1(const int* __restrict__ src,
                                                   const int* __restrict__ dst,
                                                   const float* __restrict__ w,
                                                   int* __restrict__ deg,
                                                   uint* __restrict__ csr,
                                                   const float* __restrict__ X,
                                                   const float* __restrict__ W,
                                                   const float* __restrict__ W2,
                                                   const float* __restrict__ Wd,
                                                   short* __restrict__ W2T2,
                                                   short* __restrict__ WdT2,
                                                   ushort* __restrict__ H) {
    __shared__ __align__(16) short sBT[2][D][72];    // 18.4 KB (aliased as rep later)
    int tid = threadIdx.x;

    if (blockIdx.x < FILL_BLOCKS) {
        const int g = blockIdx.x & (NGROUPS - 1);
        const int s = blockIdx.x >> 2;               // slice 0..NSLICES-1
        const int lo = g * DST_PER_GROUP;
        const int hi = lo + DST_PER_GROUP;
        for (int e = s * 256 + tid; e < N_EDGES; e += NSLICES * 256) {
            int d = dst[e];                          // L3 absorbs the 4x re-scan
            if (d >= lo && d < hi) {
                uint hw = (uint)__half_as_ushort(__float2half_rn(w[e]));
                uint payload = (uint)src[e] | (hw << 16);
                int r = atomicAdd(&deg[d], 1);
                r = min(r, CAP - 1);   // safety clamp
                csr[(d << 6) + r] = payload;
            }
        }
        return;
    }

    if (blockIdx.x >= FILL_BLOCKS + MM_BLOCKS) {
        // ---------- weight-split prep ----------
        if (blockIdx.x == FILL_BLOCKS + MM_BLOCKS) {
            for (int idx = tid; idx < D * D; idx += 256) {
                int k = idx >> 6, c = idx & 63;
                float wv = W2[idx];
                ushort hi = f2bf(wv);
                W2T2[(size_t)c * D + k] = (short)hi;
                W2T2[(size_t)(D + c) * D + k] = (short)f2bf(wv - bf2f(hi));
            }
        } else {
            for (int idx = tid; idx < NCT * 16 * D; idx += 256) {
                int jj = idx >> 6, k = idx & 63;
                float wv = (jj < DHID) ? Wd[k * DHID + jj] : 0.f;
                ushort hi = f2bf(wv);
                WdT2[(size_t)jj * D + k] = (short)hi;
                WdT2[(size_t)(NCT * 16 + jj) * D + k] = (short)f2bf(wv - bf2f(hi));
            }
        }
        return;
    }

    // ---------- mfma_l1 path ----------
    for (int idx = tid; idx < D * D; idx += 256) {
        int k = idx >> 6, c = idx & 63;
        float wv = W[idx];
        ushort hi = f2bf(wv);
        sBT[0][c][k] = (short)hi;
        sBT[1][c][k] = (short)f2bf(wv - bf2f(hi));
    }
    __syncthreads();
    int wv_ = tid >> 6, lane = tid & 63, quad = lane >> 4, m = lane & 15;
    int tile = min((blockIdx.x - FILL_BLOCKS) * 4 + wv_, NTILES - 1);  // clamp (dup stores ok)
    int node0 = tile * 16;

    f32x4 acc[4] = {{0,0,0,0},{0,0,0,0},{0,0,0,0},{0,0,0,0}};
#pragma unroll
    for (int kt = 0; kt < 2; ++kt) {
        int k0 = kt * 32 + quad * 8;
        const float* xp = X + ((size_t)(node0 + m) << 6) + k0;
        float4 xa = *((const float4*)xp);
        float4 xb = *((const float4*)(xp + 4));
        float xv[8] = {xa.x, xa.y, xa.z, xa.w, xb.x, xb.y, xb.z, xb.w};
        s16x8 ahi, alo;
#pragma unroll
        for (int jj = 0; jj < 8; ++jj) {
            ushort hi = f2bf(xv[jj]);
            ahi[jj] = (short)hi;
            alo[jj] = (short)f2bf(xv[jj] - bf2f(hi));
        }
#pragma unroll
        for (int ct = 0; ct < 4; ++ct) {
            int n = ct * 16 + m;
            s16x8 bhi = *((const s16x8*)&sBT[0][n][k0]);
            s16x8 blo = *((const s16x8*)&sBT[1][n][k0]);
            acc[ct] = MFMA16(ahi, bhi, acc[ct]);
            acc[ct] = MFMA16(ahi, blo, acc[ct]);
            acc[ct] = MFMA16(alo, bhi, acc[ct]);
        }
    }
    __syncthreads();   // safe to alias rep over sBT
    short (*rep)[16][72] = (short(*)[16][72])&sBT[0][0][0];
#pragma unroll
    for (int ct = 0; ct < 4; ++ct)
#pragma unroll
        for (int r = 0; r < 4; ++r)
            rep[wv_][quad * 4 + r][ct * 16 + m] = (short)f2bf(acc[ct][r]);
#pragma unroll
    for (int half = 0; half < 2; ++half) {
        int r = (lane >> 3) + half * 8;
        int c0 = (lane & 7) * 8;
        s16x8 v = *((const s16x8*)&rep[wv_][r][c0]);
        *((s16x8*)(H + ((size_t)(node0 + r) << 6) + c0)) = v;
    }
}

// ---------------- gather + bias + swish -> bf16 activation (layer 1) ----------------
__global__ __launch_bounds__(256) void gather_act(const ushort* __restrict__ H,
                                                  const int* __restrict__ deg,
                                                  const uint* __restrict__ csr,
                                                  const float* __restrict__ bias,
                                                  ushort* __restrict__ actOut) {
    int tid = threadIdx.x;
    int wave = tid >> 6, lane = tid & 63;
    int j = lane >> 3, fg = lane & 7;
    int node = blockIdx.x * 4 + wave;
    int degv = min(deg[node], CAP);
    const uint* bucket = csr + ((size_t)node << 6);

    float acc[8];
    gather_node(H, bucket, degv, j, fg, acc);
    if (j == 0) {
        float4 ba = ((const float4*)bias)[fg * 2];
        float4 bb = ((const float4*)bias)[fg * 2 + 1];
        float r0 = swishf(acc[0] + ba.x);
        float r1 = swishf(acc[1] + ba.y);
        float r2 = swishf(acc[2] + ba.z);
        float r3 = swishf(acc[3] + ba.w);
        float r4 = swishf(acc[4] + bb.x);
        float r5 = swishf(acc[5] + bb.y);
        float r6 = swishf(acc[6] + bb.z);
        float r7 = swishf(acc[7] + bb.w);
        uint4 u;
        u.x = (uint)f2bf(r0) | ((uint)f2bf(r1) << 16);
        u.y = (uint)f2bf(r2) | ((uint)f2bf(r3) << 16);
        u.z = (uint)f2bf(r4) | ((uint)f2bf(r5) << 16);
        u.w = (uint)f2bf(r6) | ((uint)f2bf(r7) << 16);
        *((uint4*)(actOut + ((size_t)node << 6) + (fg << 3))) = u;
    }
}

// ---- fused: layer-2 gather + W2 matmul + bias + swish + MLP head, one 16-node tile/block ----
__global__ __launch_bounds__(256) void gather_tail(const ushort* __restrict__ act1,
                                                   const int* __restrict__ deg,
                                                   const uint* __restrict__ csr,
                                                   const short* __restrict__ W2T2,
                                                   const float* __restrict__ b2,
                                                   const short* __restrict__ WdT2,
                                                   const float* __restrict__ bd,
                                                   const float* __restrict__ Wo,
                                                   const float* __restrict__ bo,
                                                   float* __restrict__ out) {
    __shared__ __align__(16) float sAgg[16][72];    // 4.6 KB fp32 aggregates
    __shared__ __align__(16) short sAct2[16][72];   // 2.3 KB bf16 act2 tile
    __shared__ float sPart[4][16];                  // per-wave head partials
    int tid = threadIdx.x;
    int wv = tid >> 6, lane = tid & 63;
    int j = lane >> 3, fg = lane & 7;
    int quad = lane >> 4, m = lane & 15;
    int node0 = blockIdx.x * 16;

    // ---- phase 0: gather 4 nodes per wave ----
    for (int t = 0; t < 4; ++t) {
        int nl = wv * 4 + t;
        int node = node0 + nl;
        int degv = min(deg[node], CAP);
        const uint* bucket = csr + ((size_t)node << 6);
        float acc[8];
        gather_node(act1, bucket, degv, j, fg, acc);
        if (j == 0) {
            float4 u0 = {acc[0], acc[1], acc[2], acc[3]};
            float4 u1 = {acc[4], acc[5], acc[6], acc[7]};
            *((float4*)&sAgg[nl][fg * 8]) = u0;
            *((float4*)&sAgg[nl][fg * 8 + 4]) = u1;
        }
    }
    __syncthreads();

    // ---- phase A: act2 = swish(agg @ W2 + b2), wave wv -> col-tile wv ----
    {
        f32x4 acc = {0, 0, 0, 0};
        int n = wv * 16 + m;
#pragma unroll
        for (int kt = 0; kt < 2; ++kt) {
            int k0 = kt * 32 + quad * 8;
            float4 xa = *((const float4*)&sAgg[m][k0]);
            float4 xb = *((const float4*)&sAgg[m][k0 + 4]);
            float xv[8] = {xa.x, xa.y, xa.z, xa.w, xb.x, xb.y, xb.z, xb.w};
            s16x8 ahi, alo;
#pragma unroll
            for (int jj = 0; jj < 8; ++jj) {
                ushort hi = f2bf(xv[jj]);
                ahi[jj] = (short)hi;
                alo[jj] = (short)f2bf(xv[jj] - bf2f(hi));
            }
            s16x8 bhi = *((const s16x8*)(W2T2 + (size_t)n * D + k0));
            s16x8 blo = *((const s16x8*)(W2T2 + (size_t)(D + n) * D + k0));
            acc = MFMA16(ahi, bhi, acc);
            acc = MFMA16(ahi, blo, acc);
            acc = MFMA16(alo, bhi, acc);
        }
        float bv = b2[n];
#pragma unroll
        for (int r = 0; r < 4; ++r)
            sAct2[quad * 4 + r][n] = (short)f2bf(swishf(acc[r] + bv));
    }
    __syncthreads();

    // ---- phase B: head over col-tiles {wv, wv+4} ----
    float part[4] = {0, 0, 0, 0};
#pragma unroll
    for (int cc = 0; cc < 2; ++cc) {
        int ct = wv + cc * 4;
        if (ct < NCT) {
            f32x4 acc = {0, 0, 0, 0};
            int n = ct * 16 + m;
#pragma unroll
            for (int kt = 0; kt < 2; ++kt) {
                int k0 = kt * 32 + quad * 8;
                s16x8 a = *((const s16x8*)&sAct2[m][k0]);
                s16x8 bhi = *((const s16x8*)(WdT2 + (size_t)n * D + k0));
                s16x8 blo = *((const s16x8*)(WdT2 + (size_t)(NCT * 16 + n) * D + k0));
                acc = MFMA16(a, bhi, acc);
                acc = MFMA16(a, blo, acc);
            }
            float bdv = (n < DHID) ? bd[n] : 0.f;
            float wov = (n < DHID) ? Wo[n] : 0.f;
#pragma unroll
            for (int r = 0; r < 4; ++r)
                part[r] = fmaf(swishf(acc[r] + bdv), wov, part[r]);
        }
    }
#pragma unroll
    for (int r = 0; r < 4; ++r) {
        part[r] += __shfl_xor(part[r], 1, 64);
        part[r] += __shfl_xor(part[r], 2, 64);
        part[r] += __shfl_xor(part[r], 4, 64);
        part[r] += __shfl_xor(part[r], 8, 64);
    }
    if (m == 0) {
#pragma unroll
        for (int r = 0; r < 4; ++r)
            sPart[wv][quad * 4 + r] = part[r];
    }
    __syncthreads();
    if (tid < 16) {
        float z = sPart[0][tid] + sPart[1][tid] + sPart[2][tid] + sPart[3][tid] + bo[0];
        out[node0 + tid] = 1.f / (1.f + __expf(-z));
    }
}

extern "C" void kernel_launch(void* const* d_in, const int* in_sizes, int n_in,
                              void* d_out, int out_size, void* d_ws, size_t ws_size,
                              hipStream_t stream) {
    const float* x   = (const float*)d_in[0];
    const int* esrc  = (const int*)d_in[1];
    const int* edst  = (const int*)d_in[2];
    const float* ew  = (const float*)d_in[3];
    const float* W1  = (const float*)d_in[4];
    const float* b1  = (const float*)d_in[5];
    const float* W2  = (const float*)d_in[6];
    const float* b2  = (const float*)d_in[7];
    const float* Wd  = (const float*)d_in[8];
    const float* bd  = (const float*)d_in[9];
    const float* Wo  = (const float*)d_in[10];
    const float* bo  = (const float*)d_in[11];
    float* out = (float*)d_out;

    char* ws = (char*)d_ws;
    ushort* H1   = (ushort*)ws;  ws += (size_t)N_NODES * D * sizeof(ushort);   // 6.4 MB
    ushort* act1 = (ushort*)ws;  ws += (size_t)N_NODES * D * sizeof(ushort);   // 6.4 MB
    uint* csr    = (uint*)ws;    ws += (size_t)N_NODES * CAP * sizeof(uint);   // 12.8 MB (not zeroed)
    int* deg     = (int*)ws;     ws += (size_t)N_NODES * sizeof(int);          // 200 KB
    short* W2T2  = (short*)ws;   ws += (size_t)2 * D * D * sizeof(short);      // 16 KB
    short* WdT2  = (short*)ws;   ws += (size_t)2 * NCT * 16 * D * sizeof(short); // 28.7 KB

    const int gBlocks = N_NODES / 4;   // 12500

    // ---- only deg needs zeroing (200 KB) ----
    hipMemsetAsync(deg, 0, (size_t)N_NODES * sizeof(int), stream);

    // ---- fused: XCD-partitioned fill + layer-1 matmul + weight prep ----
    fill_and_l1<<<FILL_BLOCKS + MM_BLOCKS + 2, 256, 0, stream>>>(
        esrc, edst, ew, deg, csr, x, W1, W2, Wd, W2T2, WdT2, H1);

    // ---- layer 1 gather (+bias+swish) ----
    gather_act<<<gBlocks, 256, 0, stream>>>(H1, deg, csr, b1, act1);

    // ---- fused: layer-2 gather + W2 matmul + swish + MLP head ----
    gather_tail<<<NTILES, 256, 0, stream>>>(act1, deg, csr, W2T2, b2, WdT2, bd, Wo, bo, out);
}